// Round 4
// baseline (1550.930 us; speedup 1.0000x reference)
//
#include <hip/hip_runtime.h>
#include <hip/hip_bf16.h>
#include <stdint.h>

// CubicModel: out = feats(feats(x)@W0^T + b0)@W1^T + b1
// feats(v) = [v, v_i*v_j (i<=j), v^3], d=512, K=132352
//
// R4: featgen FUSED into the GEMM. A-tile (512x64 bf16 feats) computed
//     in-register from x (1MB, L2-resident) and ds_written swizzled.
//     Global traffic = W only (406MB total -> 64us BW floor).
//     LDS: A dbuf 2x64K + B dbuf 2x16K = 160KB, ONE barrier per K-step.
//     (R3: 14.5K cyc/step, A-tile HBM/L3 fetch 64KB/step mostly exposed.)

#define D_IN      512
#define BATCH     512
#define K_TOT     132352
#define QUAD_BASE 512
#define CUBE_BASE 131840
#define BN        128
#define BK        64          // LDS row = 128 B

typedef __attribute__((ext_vector_type(8))) __bf16 bf16x8;
typedef __attribute__((ext_vector_type(4))) float  f32x4;

__device__ __forceinline__ uint32_t f2bf(float f) {
    union { float f; uint32_t u; } v; v.f = f;
    uint32_t u = v.u;
    return (u + 0x7FFFu + ((u >> 16) & 1u)) >> 16;   // RNE
}

// quad feature index: q -> (i,j), i<=j<512, q = i*(1025-i)/2 + (j-i)
__device__ __forceinline__ void decode_quad(int q, int& oi, int& oj) {
    // disc = 1050625-8q = (1025-2i)^2 at row starts; both < 2^24 -> exact
    float s = sqrtf((float)(1050625 - 8 * q));
    int i = (int)((1025.0f - s) * 0.5f);
    i = i < 0 ? 0 : (i > 511 ? 511 : i);
    while (i < 511 && (i + 1) * (1025 - (i + 1)) / 2 <= q) ++i;
    while (i > 0 && i * (1025 - i) / 2 > q) --i;
    oi = i; oj = i + (q - i * (1025 - i) / 2);
}

// compute feats for window [kw, kw+64) rows {tid>>3 + p*128} chunk tid&7,
// write bf16 swizzled into Ab. Region bounds (512, 131840) are %64==0, so a
// whole step is in one region -> uniform branch.
__device__ __forceinline__ void stage_A(const float* __restrict__ X,
                                        uint8_t* __restrict__ Ab,
                                        int kw, int tid) {
    const int c  = tid & 7;
    const int r0 = tid >> 3;
    const int k  = kw + c * 8;
    float v[4][8];
    if (k < QUAD_BASE) {                       // linear
        #pragma unroll
        for (int p = 0; p < 4; ++p) {
            const float* row = X + (size_t)(r0 + p * 128) * D_IN;
            float4 a = *(const float4*)(row + k);
            float4 b = *(const float4*)(row + k + 4);
            v[p][0]=a.x; v[p][1]=a.y; v[p][2]=a.z; v[p][3]=a.w;
            v[p][4]=b.x; v[p][5]=b.y; v[p][6]=b.z; v[p][7]=b.w;
        }
    } else if (k >= CUBE_BASE) {               // cube
        const int tt = k - CUBE_BASE;
        #pragma unroll
        for (int p = 0; p < 4; ++p) {
            const float* row = X + (size_t)(r0 + p * 128) * D_IN;
            float4 a = *(const float4*)(row + tt);
            float4 b = *(const float4*)(row + tt + 4);
            v[p][0]=a.x*a.x*a.x; v[p][1]=a.y*a.y*a.y; v[p][2]=a.z*a.z*a.z; v[p][3]=a.w*a.w*a.w;
            v[p][4]=b.x*b.x*b.x; v[p][5]=b.y*b.y*b.y; v[p][6]=b.z*b.z*b.z; v[p][7]=b.w*b.w*b.w;
        }
    } else {                                   // quad
        int i0, j0; decode_quad(k - QUAD_BASE, i0, j0);
        #pragma unroll
        for (int p = 0; p < 4; ++p) {
            const float* row = X + (size_t)(r0 + p * 128) * D_IN;
            int i = i0, j = j0;
            float xi = row[i];
            #pragma unroll
            for (int e = 0; e < 8; ++e) {
                v[p][e] = xi * row[j];
                ++j;
                if (j == 512) { ++i; j = i; xi = row[i]; }
            }
        }
    }
    #pragma unroll
    for (int p = 0; p < 4; ++p) {
        const int r = r0 + p * 128;
        uint4 pk;
        pk.x = f2bf(v[p][0]) | (f2bf(v[p][1]) << 16);
        pk.y = f2bf(v[p][2]) | (f2bf(v[p][3]) << 16);
        pk.z = f2bf(v[p][4]) | (f2bf(v[p][5]) << 16);
        pk.w = f2bf(v[p][6]) | (f2bf(v[p][7]) << 16);
        *(uint4*)(Ab + r * 128 + ((c ^ (r & 7)) * 16)) = pk;   // proven conflict-free
    }
}

// ---------------- fused GEMM ----------------
// C[512][ldc] += feats(X)[512][K] * W_f32[n][K]^T (+bias by ks==0 blocks)
// 1024 thr = 16 waves (8m x 2n), wave tile 64x64, mfma 16x16x32, acc 4x4.
// LDS: A0,A1 64KB each; B0,B1 16KB each = 160KB dynamic.
__global__ __launch_bounds__(1024, 1) void gemm_fused(
    const float* __restrict__ X,
    const float* __restrict__ W,
    float* __restrict__ C, int ldc,
    const float* __restrict__ bias, int split_steps)
{
    extern __shared__ uint8_t smem[];
    const int tid  = threadIdx.x;
    const int lane = tid & 63;
    const int wave = tid >> 6;
    const int wm   = wave >> 1;                // 0..7
    const int wn   = wave & 1;                 // 0..1
    const int n0   = blockIdx.x * BN;
    const int ks   = blockIdx.y;

    const int kbeg = ks * split_steps * BK;
    const int kend = min(K_TOT, kbeg + split_steps * BK);
    if (kbeg >= kend) return;                  // ks==0 always has work -> bias safe
    const int nt = (kend - kbeg) / BK;

    // B staging: thread -> (row=tid>>3, chunk=tid&7)
    const int brow   = tid >> 3;
    const int bchunk = tid & 7;
    const float* const wsrc = W + (size_t)(n0 + brow) * K_TOT + bchunk * 8;
    const uint32_t boff = (uint32_t)brow * 128 + (uint32_t)((bchunk ^ (brow & 7)) * 16);

    // ---- prologue: tile 0 into buf0 ----
    {
        float4 w0 = *(const float4*)(wsrc + kbeg);
        float4 w1 = *(const float4*)(wsrc + kbeg + 4);
        stage_A(X, smem, kbeg, tid);
        uint4 pk;
        pk.x = f2bf(w0.x) | (f2bf(w0.y) << 16);
        pk.y = f2bf(w0.z) | (f2bf(w0.w) << 16);
        pk.z = f2bf(w1.x) | (f2bf(w1.y) << 16);
        pk.w = f2bf(w1.z) | (f2bf(w1.w) << 16);
        *(uint4*)(smem + 131072 + boff) = pk;
    }
    __syncthreads();

    f32x4 acc[4][4] = {};
    const int fr = lane & 15;
    const int h  = lane >> 4;

    for (int t = 0; t < nt; ++t) {
        const uint32_t cur = (uint32_t)(t & 1);
        uint8_t* const Ab = smem + cur * 65536u;
        uint8_t* const Bb = smem + 131072u + cur * 16384u;
        const bool pre = (t + 1 < nt);
        const int kkn = kbeg + (t + 1) * BK;

        // issue next W loads early (HBM latency covered by MFMA phase)
        float4 nw0, nw1;
        if (pre) {
            nw0 = *(const float4*)(wsrc + kkn);
            nw1 = *(const float4*)(wsrc + kkn + 4);
        }

        // ---- MFMA phase on tile t ----
        #pragma unroll
        for (int s = 0; s < 2; ++s) {
            bf16x8 a[4];
            #pragma unroll
            for (int mf = 0; mf < 4; ++mf) {
                const int row = wm * 64 + mf * 16 + fr;
                a[mf] = *(const bf16x8*)(Ab + row * 128 + (((s * 4 + h) ^ (row & 7)) * 16));
            }
            #pragma unroll
            for (int nf = 0; nf < 4; ++nf) {
                const int row = wn * 64 + nf * 16 + fr;
                bf16x8 b = *(const bf16x8*)(Bb + row * 128 + (((s * 4 + h) ^ (row & 7)) * 16));
                #pragma unroll
                for (int mf = 0; mf < 4; ++mf)
                    acc[mf][nf] = __builtin_amdgcn_mfma_f32_16x16x32_bf16(a[mf], b, acc[mf][nf], 0, 0, 0);
            }
        }

        // ---- stage tile t+1 into the other buffers ----
        // (safe pre-barrier: buf[cur^1] was last READ in iter t-1, and the
        //  barrier at end of iter t-1 ordered that read before these writes)
        if (pre) {
            stage_A(X, smem + (cur ^ 1u) * 65536u, kkn, tid);
            uint4 pk;
            pk.x = f2bf(nw0.x) | (f2bf(nw0.y) << 16);
            pk.y = f2bf(nw0.z) | (f2bf(nw0.w) << 16);
            pk.z = f2bf(nw1.x) | (f2bf(nw1.y) << 16);
            pk.w = f2bf(nw1.z) | (f2bf(nw1.w) << 16);
            *(uint4*)(smem + 131072u + (cur ^ 1u) * 16384u + boff) = pk;
        }
        __syncthreads();
    }

    // epilogue: C/D layout col=lane&15, row=(lane>>4)*4+reg  [m89-verified]
    const bool dob = (ks == 0);
    const int rbase = wm * 64 + (lane >> 4) * 4;
    const int cbase = n0 + wn * 64 + (lane & 15);
    #pragma unroll
    for (int nf = 0; nf < 4; ++nf) {
        const int col = cbase + nf * 16;
        const float bv = dob ? bias[col] : 0.0f;
        #pragma unroll
        for (int mf = 0; mf < 4; ++mf) {
            const int row = rbase + mf * 16;
            #pragma unroll
            for (int r = 0; r < 4; ++r)
                unsafeAtomicAdd(&C[(size_t)(row + r) * ldc + col], acc[mf][nf][r] + bv);
        }
    }
}

// ---------------- host ----------------
extern "C" void kernel_launch(void* const* d_in, const int* in_sizes, int n_in,
                              void* d_out, int out_size, void* d_ws, size_t ws_size,
                              hipStream_t stream)
{
    const float* x  = (const float*)d_in[0];
    const float* W0 = (const float*)d_in[1];
    const float* b0 = (const float*)d_in[2];
    const float* W1 = (const float*)d_in[3];
    const float* b1 = (const float*)d_in[4];
    float* out = (float*)d_out;

    float* hbuf = (float*)d_ws;                        // [512][512]
    const size_t hbytes = (size_t)BATCH * 512 * 4;

    static int lds_set = 0;
    if (!lds_set) {    // host-side, idempotent, outside stream -> capture-safe
        hipFuncSetAttribute((const void*)gemm_fused,
                            hipFuncAttributeMaxDynamicSharedMemorySize, 163840);
        lds_set = 1;
    }

    hipMemsetAsync(hbuf, 0, hbytes, stream);
    hipMemsetAsync(out, 0, (size_t)out_size * 4, stream);

    // layer 0: h = feats(x) @ W0^T + b0     N=512 -> grid (4, 64)
    {
        const int S = 64;
        const int ss = (K_TOT / BK + S - 1) / S;       // 33
        gemm_fused<<<dim3(512 / BN, S), 1024, 163840, stream>>>(
            x, W0, hbuf, 512, b0, ss);
    }
    // layer 1: out = feats(h) @ W1^T + b1   N=256 -> grid (2, 128)
    {
        const int S = 128;
        const int ss = (K_TOT / BK + S - 1) / S;       // 17
        gemm_fused<<<dim3(256 / BN, S), 1024, 163840, stream>>>(
            hbuf, W1, out, 256, b1, ss);
    }
}

// Round 5
// 410.144 us; speedup vs baseline: 3.7814x; 3.7814x over previous
//
#include <hip/hip_runtime.h>
#include <hip/hip_bf16.h>
#include <stdint.h>

// CubicModel: out = feats(feats(x)@W0^T + b0)@W1^T + b1
// feats(v) = [v, v_i*v_j (i<=j), v^3], d=512, K=132352
//
// R5: R4 fused structure, rewritten to fit the 128-reg/lane budget
//     (R4 spilled: 852MB scratch writes/dispatch, MfmaUtil 2.7%).
//     stage_A streams one row-slice at a time (unroll 1), quad fast path
//     uses float4 loads when the 8-run doesn't wrap a triu row.

#define D_IN      512
#define BATCH     512
#define K_TOT     132352
#define QUAD_BASE 512
#define CUBE_BASE 131840
#define BN        128
#define BK        64          // LDS row = 128 B

typedef __attribute__((ext_vector_type(8))) __bf16 bf16x8;
typedef __attribute__((ext_vector_type(4))) float  f32x4;

__device__ __forceinline__ uint32_t f2bf(float f) {
    union { float f; uint32_t u; } v; v.f = f;
    uint32_t u = v.u;
    return (u + 0x7FFFu + ((u >> 16) & 1u)) >> 16;   // RNE
}

__device__ __forceinline__ uint4 pack8(float a0, float a1, float a2, float a3,
                                       float a4, float a5, float a6, float a7) {
    uint4 pk;
    pk.x = f2bf(a0) | (f2bf(a1) << 16);
    pk.y = f2bf(a2) | (f2bf(a3) << 16);
    pk.z = f2bf(a4) | (f2bf(a5) << 16);
    pk.w = f2bf(a6) | (f2bf(a7) << 16);
    return pk;
}

// quad feature index: q -> (i,j), i<=j<512, q = i*(1025-i)/2 + (j-i)
__device__ __forceinline__ void decode_quad(int q, int& oi, int& oj) {
    // disc = 1050625-8q = (1025-2i)^2 at row starts; both < 2^24 -> exact
    float s = sqrtf((float)(1050625 - 8 * q));
    int i = (int)((1025.0f - s) * 0.5f);
    i = i < 0 ? 0 : (i > 511 ? 511 : i);
    while (i < 511 && (i + 1) * (1025 - (i + 1)) / 2 <= q) ++i;
    while (i > 0 && i * (1025 - i) / 2 > q) --i;
    oi = i; oj = i + (q - i * (1025 - i) / 2);
}

// stage feats for window [kw,kw+64): thread -> chunk c=tid&7 of rows
// {r0, r0+128, r0+256, r0+384}, r0=tid>>3. Streams one row at a time
// (small live set). Swizzled write offset is p-invariant (r&7 == r0&7).
__device__ __forceinline__ void stage_A(const float* __restrict__ X,
                                        uint8_t* __restrict__ Ab,
                                        int kw, int tid) {
    const int c  = tid & 7;
    const int r0 = tid >> 3;
    const int k  = kw + c * 8;
    uint8_t* const wp0 = Ab + (size_t)r0 * 128 + (uint32_t)((c ^ (r0 & 7)) * 16);

    if (k < QUAD_BASE) {                       // linear
        #pragma unroll 1
        for (int p = 0; p < 4; ++p) {
            const float* row = X + (size_t)(r0 + p * 128) * D_IN;
            float4 a = *(const float4*)(row + k);
            float4 b = *(const float4*)(row + k + 4);
            *(uint4*)(wp0 + p * (128 * 128)) = pack8(a.x, a.y, a.z, a.w, b.x, b.y, b.z, b.w);
        }
    } else if (k >= CUBE_BASE) {               // cube
        const int tt = k - CUBE_BASE;
        #pragma unroll 1
        for (int p = 0; p < 4; ++p) {
            const float* row = X + (size_t)(r0 + p * 128) * D_IN;
            float4 a = *(const float4*)(row + tt);
            float4 b = *(const float4*)(row + tt + 4);
            *(uint4*)(wp0 + p * (128 * 128)) = pack8(
                a.x * a.x * a.x, a.y * a.y * a.y, a.z * a.z * a.z, a.w * a.w * a.w,
                b.x * b.x * b.x, b.y * b.y * b.y, b.z * b.z * b.z, b.w * b.w * b.w);
        }
    } else {                                   // quad
        int i0, j0; decode_quad(k - QUAD_BASE, i0, j0);
        if (j0 <= 504) {                       // 8-run stays in triu row i0
            #pragma unroll 1
            for (int p = 0; p < 4; ++p) {
                const float* row = X + (size_t)(r0 + p * 128) * D_IN;
                const float xi = row[i0];
                float4 a = *(const float4*)(row + j0);
                float4 b = *(const float4*)(row + j0 + 4);
                *(uint4*)(wp0 + p * (128 * 128)) = pack8(
                    xi * a.x, xi * a.y, xi * a.z, xi * a.w,
                    xi * b.x, xi * b.y, xi * b.z, xi * b.w);
            }
        } else {                               // wraps one or more row ends
            #pragma unroll 1
            for (int p = 0; p < 4; ++p) {
                const float* row = X + (size_t)(r0 + p * 128) * D_IN;
                int i = i0, j = j0;
                float xi = row[i];
                float v[8];
                #pragma unroll
                for (int e = 0; e < 8; ++e) {
                    v[e] = xi * row[j];
                    ++j;
                    if (j == 512) { ++i; j = i; xi = row[i]; }
                }
                *(uint4*)(wp0 + p * (128 * 128)) = pack8(v[0], v[1], v[2], v[3],
                                                         v[4], v[5], v[6], v[7]);
            }
        }
    }
}

// ---------------- fused GEMM ----------------
// C[512][ldc] += feats(X)[512][K] * W_f32[n][K]^T (+bias by ks==0 blocks)
// 1024 thr = 16 waves (8m x 2n), wave tile 64x64, mfma 16x16x32, acc 4x4.
// LDS: A0,A1 64KB each; B0,B1 16KB each = 160KB dynamic.
__global__ __launch_bounds__(1024, 1) void gemm_fused(
    const float* __restrict__ X,
    const float* __restrict__ W,
    float* __restrict__ C, int ldc,
    const float* __restrict__ bias, int split_steps)
{
    extern __shared__ uint8_t smem[];
    const int tid  = threadIdx.x;
    const int lane = tid & 63;
    const int wave = tid >> 6;
    const int wm   = wave >> 1;                // 0..7
    const int wn   = wave & 1;                 // 0..1
    const int n0   = blockIdx.x * BN;
    const int ks   = blockIdx.y;

    const int kbeg = ks * split_steps * BK;
    const int kend = min(K_TOT, kbeg + split_steps * BK);
    if (kbeg >= kend) return;                  // ks==0 always has work -> bias safe
    const int nt = (kend - kbeg) / BK;

    // B staging: thread -> (row=tid>>3, chunk=tid&7)
    const int brow   = tid >> 3;
    const int bchunk = tid & 7;
    const float* const wsrc = W + (size_t)(n0 + brow) * K_TOT + bchunk * 8;
    const uint32_t boff = (uint32_t)brow * 128 + (uint32_t)((bchunk ^ (brow & 7)) * 16);

    // ---- prologue: tile 0 into buf0 ----
    {
        float4 w0 = *(const float4*)(wsrc + kbeg);
        float4 w1 = *(const float4*)(wsrc + kbeg + 4);
        stage_A(X, smem, kbeg, tid);
        *(uint4*)(smem + 131072 + boff) =
            pack8(w0.x, w0.y, w0.z, w0.w, w1.x, w1.y, w1.z, w1.w);
    }
    __syncthreads();

    f32x4 acc[4][4] = {};
    const int fr = lane & 15;
    const int h  = lane >> 4;

    for (int t = 0; t < nt; ++t) {
        const uint32_t cur = (uint32_t)(t & 1);
        const uint8_t* const Ab = smem + cur * 65536u;
        const uint8_t* const Bb = smem + 131072u + cur * 16384u;
        const bool pre = (t + 1 < nt);
        const int kkn = kbeg + (t + 1) * BK;

        // issue next W loads early (latency covered by MFMA phase)
        float4 nw0, nw1;
        if (pre) {
            nw0 = *(const float4*)(wsrc + kkn);
            nw1 = *(const float4*)(wsrc + kkn + 4);
        }

        // ---- MFMA phase on tile t ----
        #pragma unroll
        for (int s = 0; s < 2; ++s) {
            bf16x8 a[4];
            #pragma unroll
            for (int mf = 0; mf < 4; ++mf) {
                const int row = wm * 64 + mf * 16 + fr;
                a[mf] = *(const bf16x8*)(Ab + row * 128 + (((s * 4 + h) ^ (row & 7)) * 16));
            }
            #pragma unroll
            for (int nf = 0; nf < 4; ++nf) {
                const int row = wn * 64 + nf * 16 + fr;
                bf16x8 b = *(const bf16x8*)(Bb + row * 128 + (((s * 4 + h) ^ (row & 7)) * 16));
                #pragma unroll
                for (int mf = 0; mf < 4; ++mf)
                    acc[mf][nf] = __builtin_amdgcn_mfma_f32_16x16x32_bf16(a[mf], b, acc[mf][nf], 0, 0, 0);
            }
        }

        // ---- stage tile t+1 (other buffers; safe: they were last read in
        // iter t-1, ordered by that iter's barrier) ----
        if (pre) {
            stage_A(X, smem + (cur ^ 1u) * 65536u, kkn, tid);
            *(uint4*)(smem + 131072u + (cur ^ 1u) * 16384u + boff) =
                pack8(nw0.x, nw0.y, nw0.z, nw0.w, nw1.x, nw1.y, nw1.z, nw1.w);
        }
        __syncthreads();
    }

    // epilogue: C/D layout col=lane&15, row=(lane>>4)*4+reg  [m89-verified]
    const bool dob = (ks == 0);
    const int rbase = wm * 64 + (lane >> 4) * 4;
    const int cbase = n0 + wn * 64 + (lane & 15);
    #pragma unroll
    for (int nf = 0; nf < 4; ++nf) {
        const int col = cbase + nf * 16;
        const float bv = dob ? bias[col] : 0.0f;
        #pragma unroll
        for (int mf = 0; mf < 4; ++mf) {
            const int row = rbase + mf * 16;
            #pragma unroll
            for (int r = 0; r < 4; ++r)
                unsafeAtomicAdd(&C[(size_t)(row + r) * ldc + col], acc[mf][nf][r] + bv);
        }
    }
}

// ---------------- host ----------------
extern "C" void kernel_launch(void* const* d_in, const int* in_sizes, int n_in,
                              void* d_out, int out_size, void* d_ws, size_t ws_size,
                              hipStream_t stream)
{
    const float* x  = (const float*)d_in[0];
    const float* W0 = (const float*)d_in[1];
    const float* b0 = (const float*)d_in[2];
    const float* W1 = (const float*)d_in[3];
    const float* b1 = (const float*)d_in[4];
    float* out = (float*)d_out;

    float* hbuf = (float*)d_ws;                        // [512][512]
    const size_t hbytes = (size_t)BATCH * 512 * 4;

    static int lds_set = 0;
    if (!lds_set) {    // host-side, idempotent, outside stream -> capture-safe
        hipFuncSetAttribute((const void*)gemm_fused,
                            hipFuncAttributeMaxDynamicSharedMemorySize, 163840);
        lds_set = 1;
    }

    hipMemsetAsync(hbuf, 0, hbytes, stream);
    hipMemsetAsync(out, 0, (size_t)out_size * 4, stream);

    // layer 0: h = feats(x) @ W0^T + b0     N=512 -> grid (4, 64)
    {
        const int S = 64;
        const int ss = (K_TOT / BK + S - 1) / S;       // 33
        gemm_fused<<<dim3(512 / BN, S), 1024, 163840, stream>>>(
            x, W0, hbuf, 512, b0, ss);
    }
    // layer 1: out = feats(h) @ W1^T + b1   N=256 -> grid (2, 128)
    {
        const int S = 128;
        const int ss = (K_TOT / BK + S - 1) / S;       // 17
        gemm_fused<<<dim3(256 / BN, S), 1024, 163840, stream>>>(
            hbuf, W1, out, 256, b1, ss);
    }
}

// Round 6
// 353.821 us; speedup vs baseline: 4.3834x; 1.1592x over previous
//
#include <hip/hip_runtime.h>
#include <hip/hip_bf16.h>
#include <stdint.h>

// CubicModel: out = feats(feats(x)@W0^T + b0)@W1^T + b1
// feats(v) = [v, v_i*v_j (i<=j), v^3], d=512, K=132352
//
// R6: VALU diet on the R5 fused kernel (R5: VALUBusy 38.8% dominant,
//     manual 4-op RNE f2bf x 40 elems/thread/step).
//     - native (__bf16) casts -> v_cvt_pk_bf16_f32 (compiler-fused)
//     - hoisted swizzle/addressing (cs0/cs1; frag row offsets; row ptrs)
//     - unroll 2 staging, setprio around MFMA, dead-block-free grids

#define D_IN      512
#define BATCH     512
#define K_TOT     132352
#define QUAD_BASE 512
#define CUBE_BASE 131840
#define BN        128
#define BK        64          // LDS row = 128 B

typedef __attribute__((ext_vector_type(8))) __bf16 bf16x8;
typedef __attribute__((ext_vector_type(4))) float  f32x4;

__device__ __forceinline__ bf16x8 pack8(float a0, float a1, float a2, float a3,
                                        float a4, float a5, float a6, float a7) {
    bf16x8 r;
    r[0] = (__bf16)a0; r[1] = (__bf16)a1; r[2] = (__bf16)a2; r[3] = (__bf16)a3;
    r[4] = (__bf16)a4; r[5] = (__bf16)a5; r[6] = (__bf16)a6; r[7] = (__bf16)a7;
    return r;
}

// quad feature index: q -> (i,j), i<=j<512, q = i*(1025-i)/2 + (j-i)
__device__ __forceinline__ void decode_quad(int q, int& oi, int& oj) {
    // disc = 1050625-8q = (1025-2i)^2 at row starts; both < 2^24 -> exact
    float s = sqrtf((float)(1050625 - 8 * q));
    int i = (int)((1025.0f - s) * 0.5f);
    i = i < 0 ? 0 : (i > 511 ? 511 : i);
    while (i < 511 && (i + 1) * (1025 - (i + 1)) / 2 <= q) ++i;
    while (i > 0 && i * (1025 - i) / 2 > q) --i;
    oi = i; oj = i + (q - i * (1025 - i) / 2);
}

// stage feats for window [kw,kw+64): thread -> chunk c=tid&7 of rows
// {r0, r0+128, r0+256, r0+384}. Swizzled write offset is p-invariant.
__device__ __forceinline__ void stage_A(const float* __restrict__ X,
                                        uint8_t* __restrict__ Ab,
                                        int kw, int tid) {
    const int c  = tid & 7;
    const int r0 = tid >> 3;
    const int k  = kw + c * 8;
    uint8_t* const wp0 = Ab + (size_t)r0 * 128 + (uint32_t)((c ^ (r0 & 7)) * 16);
    const float* const xrow = X + (size_t)r0 * D_IN;

    if (k < QUAD_BASE) {                       // linear
        #pragma unroll 2
        for (int p = 0; p < 4; ++p) {
            const float* row = xrow + (size_t)p * (128 * D_IN);
            float4 a = *(const float4*)(row + k);
            float4 b = *(const float4*)(row + k + 4);
            *(bf16x8*)(wp0 + p * 16384) = pack8(a.x, a.y, a.z, a.w, b.x, b.y, b.z, b.w);
        }
    } else if (k >= CUBE_BASE) {               // cube
        const int tt = k - CUBE_BASE;
        #pragma unroll 2
        for (int p = 0; p < 4; ++p) {
            const float* row = xrow + (size_t)p * (128 * D_IN);
            float4 a = *(const float4*)(row + tt);
            float4 b = *(const float4*)(row + tt + 4);
            *(bf16x8*)(wp0 + p * 16384) = pack8(
                a.x * a.x * a.x, a.y * a.y * a.y, a.z * a.z * a.z, a.w * a.w * a.w,
                b.x * b.x * b.x, b.y * b.y * b.y, b.z * b.z * b.z, b.w * b.w * b.w);
        }
    } else {                                   // quad
        int i0, j0; decode_quad(k - QUAD_BASE, i0, j0);
        if (j0 <= 504) {                       // 8-run stays inside triu row i0
            #pragma unroll 2
            for (int p = 0; p < 4; ++p) {
                const float* row = xrow + (size_t)p * (128 * D_IN);
                const float xi = row[i0];
                float4 a = *(const float4*)(row + j0);
                float4 b = *(const float4*)(row + j0 + 4);
                *(bf16x8*)(wp0 + p * 16384) = pack8(
                    xi * a.x, xi * a.y, xi * a.z, xi * a.w,
                    xi * b.x, xi * b.y, xi * b.z, xi * b.w);
            }
        } else {                               // wraps one or more row ends
            #pragma unroll 2
            for (int p = 0; p < 4; ++p) {
                const float* row = xrow + (size_t)p * (128 * D_IN);
                int i = i0, j = j0;
                float xi = row[i];
                float v[8];
                #pragma unroll
                for (int e = 0; e < 8; ++e) {
                    v[e] = xi * row[j];
                    ++j;
                    if (j == 512) { ++i; j = i; xi = row[i]; }
                }
                *(bf16x8*)(wp0 + p * 16384) = pack8(v[0], v[1], v[2], v[3],
                                                    v[4], v[5], v[6], v[7]);
            }
        }
    }
}

// ---------------- fused GEMM ----------------
// C[512][ldc] += feats(X)[512][K] * W_f32[n][K]^T (+bias by ks==0 blocks)
// 1024 thr = 16 waves (8m x 2n), wave tile 64x64, mfma 16x16x32, acc 4x4.
// LDS: A0,A1 64KB each; B0,B1 16KB each = 160KB dynamic.
__global__ __launch_bounds__(1024, 1) void gemm_fused(
    const float* __restrict__ X,
    const float* __restrict__ W,
    float* __restrict__ C, int ldc,
    const float* __restrict__ bias, int split_steps)
{
    extern __shared__ uint8_t smem[];
    const int tid  = threadIdx.x;
    const int lane = tid & 63;
    const int wave = tid >> 6;
    const int wm   = wave >> 1;                // 0..7
    const int wn   = wave & 1;                 // 0..1
    const int n0   = blockIdx.x * BN;
    const int ks   = blockIdx.y;

    const int kbeg = ks * split_steps * BK;
    const int kend = min(K_TOT, kbeg + split_steps * BK);
    if (kbeg >= kend) return;                  // ks==0 always has work -> bias safe
    const int nt = (kend - kbeg) / BK;

    // B staging: thread -> (row=tid>>3, chunk=tid&7)
    const int brow   = tid >> 3;
    const int bchunk = tid & 7;
    const float* const wsrc = W + (size_t)(n0 + brow) * K_TOT + bchunk * 8;
    const uint32_t boff = (uint32_t)brow * 128 + (uint32_t)((bchunk ^ (brow & 7)) * 16);

    // ---- prologue: tile 0 into buf0 ----
    {
        float4 w0 = *(const float4*)(wsrc + kbeg);
        float4 w1 = *(const float4*)(wsrc + kbeg + 4);
        stage_A(X, smem, kbeg, tid);
        *(bf16x8*)(smem + 131072 + boff) =
            pack8(w0.x, w0.y, w0.z, w0.w, w1.x, w1.y, w1.z, w1.w);
    }
    __syncthreads();

    f32x4 acc[4][4] = {};
    const int fr = lane & 15;
    const int h  = lane >> 4;
    // frag addressing, hoisted: row&7 == fr&7 == lane&7 for every fragment,
    // so the swizzled chunk offset is shared: cs0 (s=0), cs1 = cs0^64 (s=1).
    uint32_t aoff[4], boffr[4];
    #pragma unroll
    for (int i = 0; i < 4; ++i) {
        aoff[i]  = (uint32_t)(wm * 64 + i * 16 + fr) * 128;
        boffr[i] = (uint32_t)(wn * 64 + i * 16 + fr) * 128;
    }
    const uint32_t cs0 = (uint32_t)((h ^ (lane & 7)) * 16);
    const uint32_t cs1 = cs0 ^ 64u;

    for (int t = 0; t < nt; ++t) {
        const uint32_t cur = (uint32_t)(t & 1);
        const uint8_t* const Ab = smem + cur * 65536u;
        const uint8_t* const Bb = smem + 131072u + cur * 16384u;
        const bool pre = (t + 1 < nt);
        const int kkn = kbeg + (t + 1) * BK;

        // issue next W loads early (latency covered by MFMA phase)
        float4 nw0, nw1;
        if (pre) {
            nw0 = *(const float4*)(wsrc + kkn);
            nw1 = *(const float4*)(wsrc + kkn + 4);
        }

        // ---- MFMA phase on tile t ----
        __builtin_amdgcn_s_setprio(1);
        #pragma unroll
        for (int s = 0; s < 2; ++s) {
            const uint32_t cs = s ? cs1 : cs0;
            bf16x8 a[4];
            #pragma unroll
            for (int mf = 0; mf < 4; ++mf)
                a[mf] = *(const bf16x8*)(Ab + aoff[mf] + cs);
            #pragma unroll
            for (int nf = 0; nf < 4; ++nf) {
                bf16x8 b = *(const bf16x8*)(Bb + boffr[nf] + cs);
                #pragma unroll
                for (int mf = 0; mf < 4; ++mf)
                    acc[mf][nf] = __builtin_amdgcn_mfma_f32_16x16x32_bf16(a[mf], b, acc[mf][nf], 0, 0, 0);
            }
        }
        __builtin_amdgcn_s_setprio(0);

        // ---- stage tile t+1 (other buffers; last read in iter t-1, ordered
        // by that iter's barrier) ----
        if (pre) {
            stage_A(X, smem + (cur ^ 1u) * 65536u, kkn, tid);
            *(bf16x8*)(smem + 131072u + (cur ^ 1u) * 16384u + boff) =
                pack8(nw0.x, nw0.y, nw0.z, nw0.w, nw1.x, nw1.y, nw1.z, nw1.w);
        }
        __syncthreads();
    }

    // epilogue: C/D layout col=lane&15, row=(lane>>4)*4+reg  [m89-verified]
    const bool dob = (ks == 0);
    const int rbase = wm * 64 + (lane >> 4) * 4;
    const int cbase = n0 + wn * 64 + (lane & 15);
    #pragma unroll
    for (int nf = 0; nf < 4; ++nf) {
        const int col = cbase + nf * 16;
        const float bv = dob ? bias[col] : 0.0f;
        #pragma unroll
        for (int mf = 0; mf < 4; ++mf) {
            const int row = rbase + mf * 16;
            #pragma unroll
            for (int r = 0; r < 4; ++r)
                unsafeAtomicAdd(&C[(size_t)(row + r) * ldc + col], acc[mf][nf][r] + bv);
        }
    }
}

// ---------------- host ----------------
extern "C" void kernel_launch(void* const* d_in, const int* in_sizes, int n_in,
                              void* d_out, int out_size, void* d_ws, size_t ws_size,
                              hipStream_t stream)
{
    const float* x  = (const float*)d_in[0];
    const float* W0 = (const float*)d_in[1];
    const float* b0 = (const float*)d_in[2];
    const float* W1 = (const float*)d_in[3];
    const float* b1 = (const float*)d_in[4];
    float* out = (float*)d_out;

    float* hbuf = (float*)d_ws;                        // [512][512]
    const size_t hbytes = (size_t)BATCH * 512 * 4;

    static int lds_set = 0;
    if (!lds_set) {    // host-side, idempotent, outside stream -> capture-safe
        hipFuncSetAttribute((const void*)gemm_fused,
                            hipFuncAttributeMaxDynamicSharedMemorySize, 163840);
        lds_set = 1;
    }

    hipMemsetAsync(hbuf, 0, hbytes, stream);
    hipMemsetAsync(out, 0, (size_t)out_size * 4, stream);

    const int TS = K_TOT / BK;                         // 2068 K-steps total

    // layer 0: h = feats(x) @ W0^T + b0     grid (4, 63) = 252 blocks, no dead
    {
        const int ss = 33;
        const int gy = (TS + ss - 1) / ss;             // 63
        gemm_fused<<<dim3(512 / BN, gy), 1024, 163840, stream>>>(
            x, W0, hbuf, 512, b0, ss);
    }
    // layer 1: out = feats(h) @ W1^T + b1   grid (2, 122) = 244 blocks, no dead
    {
        const int ss = 17;
        const int gy = (TS + ss - 1) / ss;             // 122
        gemm_fused<<<dim3(256 / BN, gy), 1024, 163840, stream>>>(
            hbuf, W1, out, 256, b1, ss);
    }
}